// Round 1
// 149.628 us; speedup vs baseline: 1.0357x; 1.0357x over previous
//
#include <hip/hip_runtime.h>
#include <cstdint>
#include <cstddef>

#define NB 16
#define NC 256
#define NN 4096
#define ND 256

typedef unsigned short u16;
typedef unsigned int u32;

typedef __attribute__((ext_vector_type(8))) short short8;
typedef __attribute__((ext_vector_type(4))) float f32x4;

__device__ __forceinline__ u16 f2bf(float f) {
  union { float f; u32 u; } v; v.f = f;
  u32 r = v.u + 0x7FFFu + ((v.u >> 16) & 1u);
  return (u16)(r >> 16);
}
__device__ __forceinline__ float bf2f(u16 h) {
  union { u32 u; float f; } v; v.u = ((u32)h) << 16; return v.f;
}

// ---------------------------------------------------------------------------
// Kernel 1: per (b, n-tile of 64) block spanning FULL C=256:
//   - read x fp32 tile (256 c x 64 n), cast -> bf16, LDS-transpose
//   - q[n] = sum_c W[0][c]*x[c][n]  (fp32, in-block reduction; no atomics)
//   - online-softmax partial: m = max q, l = sum e^{q-m}
//   - pacc[c] = sum_{n in tile} bf16(x[c][n]) * e^{q[n]-m}
//   - write xbT[b][n][c] bf16 (transposed, K-contiguous for the GEMM)
// Replaces k_zero + k_cast_transpose_q + k_softmax + k_xs of the old pipeline.
// ---------------------------------------------------------------------------
__global__ __launch_bounds__(256) void k_fuse1(const float* __restrict__ x,
                                               const float* __restrict__ W,
                                               u16* __restrict__ xbT,
                                               float* __restrict__ pm,
                                               float* __restrict__ pl,
                                               float* __restrict__ pacc) {
  __shared__ __align__(16) u16 tile[64 * 264];   // [n][c], pad 264 (33,792 B)
  __shared__ float qred[16 * 64];
  __shared__ float qv[64];
  __shared__ float pv[64];
  const int t = threadIdx.x;
  const int b = blockIdx.y, n0 = blockIdx.x * 64;
  const float* xb = x + (size_t)b * NC * NN + n0;
  const int nl = (t & 15) * 4;   // n within tile (4 floats)
  const int cg = t >> 4;         // c group 0..15
  float q0 = 0.f, q1 = 0.f, q2 = 0.f, q3 = 0.f;
#pragma unroll
  for (int i = 0; i < 16; ++i) {
    const int c = cg + i * 16;                 // 0..255
    float4 v = *(const float4*)(xb + (size_t)c * NN + nl);
    const float wq = W[c];
    q0 += wq * v.x; q1 += wq * v.y; q2 += wq * v.z; q3 += wq * v.w;
    tile[(nl + 0) * 264 + c] = f2bf(v.x);
    tile[(nl + 1) * 264 + c] = f2bf(v.y);
    tile[(nl + 2) * 264 + c] = f2bf(v.z);
    tile[(nl + 3) * 264 + c] = f2bf(v.w);
  }
  qred[cg * 64 + nl + 0] = q0;
  qred[cg * 64 + nl + 1] = q1;
  qred[cg * 64 + nl + 2] = q2;
  qred[cg * 64 + nl + 3] = q3;
  __syncthreads();
  if (t < 64) {
    float s = 0.f;
#pragma unroll
    for (int k = 0; k < 16; ++k) s += qred[k * 64 + t];
    qv[t] = s;
  }
  __syncthreads();
  float m = qv[0];
#pragma unroll 16
  for (int n = 1; n < 64; ++n) m = fmaxf(m, qv[n]);   // LDS broadcast reads
  if (t < 64) pv[t] = __expf(qv[t] - m);
  __syncthreads();
  // partial weighted sum: acc = sum_n bf16(x[c=t][n]) * e^{q[n]-m}
  float acc = 0.f;
#pragma unroll 8
  for (int n = 0; n < 64; ++n) acc += bf2f(tile[n * 264 + t]) * pv[n];
  pacc[((size_t)b * 64 + blockIdx.x) * NC + t] = acc;
  if (t == 0) {
    float l = 0.f;
    for (int n = 0; n < 64; ++n) l += pv[n];
    pm[b * 64 + blockIdx.x] = m;
    pl[b * 64 + blockIdx.x] = l;
  }
  // write transposed bf16 tile: 64 rows x 512 B, fully coalesced 16B stores
  u16* ob = xbT + (size_t)(b * NN + n0) * NC;
#pragma unroll
  for (int i = 0; i < 8; ++i) {
    const int e = t + i * 256;
    const int rn = e >> 5;           // 0..63
    const int rc = (e & 31) * 8;     // 0..248
    *(short8*)(ob + (size_t)rn * NC + rc) = *(const short8*)&tile[rn * 264 + rc];
  }
}

// ---------------------------------------------------------------------------
// Kernel 2: per batch (16 blocks):
//   M = max_i m_i; L = sum_i e^{m_i-M} l_i; xs[c] = sum_i e^{m_i-M} pacc_i[c] / L
//   ctx[d] = sum_c W[1+d][c] * xs[c]
//   + Wv bf16 cast (rows b*16 .. b*16+15) folded in.
// Replaces k_ctx + k_castwv (and the softmax combine).
// ---------------------------------------------------------------------------
__global__ __launch_bounds__(256) void k_combine(const float* __restrict__ W,
                                                 const float* __restrict__ pm,
                                                 const float* __restrict__ pl,
                                                 const float* __restrict__ pacc,
                                                 float* __restrict__ ctx,
                                                 u16* __restrict__ wvb) {
  __shared__ float sm[64], sl[64], sw[64];
  __shared__ float sx[NC];
  const int b = blockIdx.x, t = threadIdx.x;
  if (t < 64) { sm[t] = pm[b * 64 + t]; sl[t] = pl[b * 64 + t]; }
  __syncthreads();
  float M = -3.4e38f;
#pragma unroll 16
  for (int i = 0; i < 64; ++i) M = fmaxf(M, sm[i]);
  if (t < 64) sw[t] = __expf(sm[t] - M);
  __syncthreads();
  float L = 0.f;
#pragma unroll 16
  for (int i = 0; i < 64; ++i) L += sw[i] * sl[i];
  float xsc = 0.f;
#pragma unroll 8
  for (int i = 0; i < 64; ++i) xsc += sw[i] * pacc[((size_t)b * 64 + i) * NC + t];
  sx[t] = xsc / L;
  __syncthreads();
  const float* wk = W + (size_t)(1 + t) * NC;
  float a = 0.f;
#pragma unroll 4
  for (int c = 0; c < NC; ++c) a += wk[c] * sx[c];
  ctx[b * NC + t] = a;
  // Wv cast: 16 rows per block
  const float* wv = W + (size_t)(1 + ND) * NC + (size_t)b * 16 * NC;
  u16* wo = wvb + (size_t)b * 16 * NC;
#pragma unroll
  for (int i = 0; i < 16; ++i) wo[i * NC + t] = f2bf(wv[i * NC + t]);
}

// ---------------------------------------------------------------------------
// Kernel 3: out[b][d][n] = relu( (Wv @ x)[d][n] ) * ctx[b][d]
// bf16 MFMA 16x16x32. BM=256 (full D per block -> xbT read EXACTLY ONCE),
// BN=128, BK=64, 512 threads = 8 waves (4 d x 2 n), 64x64 tile per wave.
// XOR-swizzled LDS in 16B chunks (phys = chunk ^ (row&7)); swizzle applied on
// the global source per lane so global_load_lds keeps a linear LDS dest.
// ---------------------------------------------------------------------------
#define BM 256
#define BN 128
#define BK 64

__global__ __launch_bounds__(512) void k_gemm(const u16* __restrict__ xbT,
                                              const u16* __restrict__ wvb,
                                              const float* __restrict__ ctx,
                                              float* __restrict__ out) {
  __shared__ __align__(16) u16 As[BM * BK];   // 32 KB
  __shared__ __align__(16) u16 Bs[BN * BK];   // 16 KB
  const int t = threadIdx.x;
  const int b = blockIdx.y;
  const int n0 = blockIdx.x * BN;
  const int lane = t & 63, w = t >> 6;
  const int wd = (w >> 1) * 64, wn = (w & 1) * 64;
  const int quad = lane >> 4, l15 = lane & 15;

  f32x4 acc[4][4];
#pragma unroll
  for (int mi = 0; mi < 4; ++mi)
#pragma unroll
    for (int ni = 0; ni < 4; ++ni)
      acc[mi][ni] = (f32x4){0.f, 0.f, 0.f, 0.f};

  // staging: thread t -> row (t>>3) (+64 per issue), phys chunk t&7,
  // fetches logical chunk (t&7)^(row&7) of that row.
  const int rstg = t >> 3;                               // 0..63
  const int l8 = ((t & 7) ^ (rstg & 7)) * 8;             // logical u16 offset
  const u16* gA = wvb + (size_t)rstg * NC + l8;
  const u16* gB = xbT + (size_t)(b * NN + n0 + rstg) * NC + l8;
  const int ldst = 8 * t;                                // u16 offset in LDS

  // fragment-read phys chunks (row&7 == l15&7 since wd, 16*mi are 0 mod 8)
  const int pq0 = ((0 * 4 + quad) ^ (l15 & 7)) * 8;
  const int pq1 = ((1 * 4 + quad) ^ (l15 & 7)) * 8;

  for (int kk = 0; kk < NC; kk += BK) {
    __syncthreads();
#pragma unroll
    for (int i = 0; i < 4; ++i)
      __builtin_amdgcn_global_load_lds(
          (const __attribute__((address_space(1))) u32*)(gA + kk + (size_t)(64 * i) * NC),
          (__attribute__((address_space(3))) u32*)(As + 4096 * i + ldst), 16, 0, 0);
#pragma unroll
    for (int i = 0; i < 2; ++i)
      __builtin_amdgcn_global_load_lds(
          (const __attribute__((address_space(1))) u32*)(gB + kk + (size_t)(64 * i) * NC),
          (__attribute__((address_space(3))) u32*)(Bs + 4096 * i + ldst), 16, 0, 0);
    __syncthreads();

#pragma unroll
    for (int kq = 0; kq < 2; ++kq) {
      const int pq = kq ? pq1 : pq0;
      short8 af[4], bfr[4];
#pragma unroll
      for (int mi = 0; mi < 4; ++mi)
        af[mi] = *(const short8*)&As[(wd + mi * 16 + l15) * BK + pq];
#pragma unroll
      for (int ni = 0; ni < 4; ++ni)
        bfr[ni] = *(const short8*)&Bs[(wn + ni * 16 + l15) * BK + pq];
#pragma unroll
      for (int mi = 0; mi < 4; ++mi)
#pragma unroll
        for (int ni = 0; ni < 4; ++ni)
          acc[mi][ni] = __builtin_amdgcn_mfma_f32_16x16x32_bf16(af[mi], bfr[ni],
                                                                acc[mi][ni], 0, 0, 0);
    }
  }

#pragma unroll
  for (int mi = 0; mi < 4; ++mi) {
#pragma unroll
    for (int r = 0; r < 4; ++r) {
      const int d = wd + mi * 16 + quad * 4 + r;
      const float cx = ctx[b * NC + d];
      float* op = out + (size_t)(b * NC + d) * NN + n0 + wn + l15;
#pragma unroll
      for (int ni = 0; ni < 4; ++ni) {
        float v = acc[mi][ni][r];
        op[ni * 16] = fmaxf(v, 0.f) * cx;
      }
    }
  }
}

// ---------------------------------------------------------------------------
extern "C" void kernel_launch(void* const* d_in, const int* in_sizes, int n_in,
                              void* d_out, int out_size, void* d_ws, size_t ws_size,
                              hipStream_t stream) {
  const float* x = (const float*)d_in[0];
  const float* W = (const float*)d_in[1];
  float* out = (float*)d_out;

  char* ws = (char*)d_ws;
  u16* xbT    = (u16*)ws;                                 // 33,554,432 B
  float* pacc = (float*)(ws + 33554432);                  //  1,048,576 B
  float* pm   = (float*)(ws + 34603008);                  //      4,096 B
  float* pl   = (float*)(ws + 34607104);                  //      4,096 B
  float* ctx  = (float*)(ws + 34611200);                  //     16,384 B
  u16* wvb    = (u16*)(ws + 34627584);                    //    131,072 B

  k_fuse1<<<dim3(64, 16), 256, 0, stream>>>(x, W, xbT, pm, pl, pacc);
  k_combine<<<16, 256, 0, stream>>>(W, pm, pl, pacc, ctx, wvb);
  k_gemm<<<dim3(32, 16), 512, 0, stream>>>(xbT, wvb, ctx, out);
}